// Round 1
// baseline (8665.741 us; speedup 1.0000x reference)
//
#include <hip/hip_runtime.h>
#include <math.h>
#include <string.h>

// ---------------- problem constants ----------------
#define E_EDGES 40000
#define N_NODES 80000
#define MULC 50
#define XSTR 450      // MUL*9 per node

// ---- sign-search knobs for the 5 tie-ambiguous W3J tensors ----
// Round 1: exact-tie first-occurrence convention; S222 choice is 6/7 likely.
#define S111 1.0
#define S122 1.0
#define S212 1.0
#define S221 1.0
#define S222 1.0

struct W3J { float v[615]; };

// ---------------- host: build W3J tensors ----------------
static void build_w3j(W3J& w) {
    const double s3 = sqrt(3.0), s5 = sqrt(5.0), s15 = sqrt(15.0);
    struct Mono { int a, b, c; double co; };
    Mono Y[3][5][3]; int nm[3][5];
    for (int l = 0; l < 3; l++) for (int c = 0; c < 5; c++) nm[l][c] = 0;
    nm[0][0] = 1; Y[0][0][0] = Mono{0,0,0,1.0};
    nm[1][0] = 1; Y[1][0][0] = Mono{1,0,0,s3};
    nm[1][1] = 1; Y[1][1][0] = Mono{0,1,0,s3};
    nm[1][2] = 1; Y[1][2][0] = Mono{0,0,1,s3};
    nm[2][0] = 1; Y[2][0][0] = Mono{1,0,1,s15};
    nm[2][1] = 1; Y[2][1][0] = Mono{1,1,0,s15};
    nm[2][2] = 3; Y[2][2][0] = Mono{0,2,0,s5};  Y[2][2][1] = Mono{2,0,0,-0.5*s5}; Y[2][2][2] = Mono{0,0,2,-0.5*s5};
    nm[2][3] = 1; Y[2][3][0] = Mono{0,1,1,s15};
    nm[2][4] = 2; Y[2][4][0] = Mono{0,0,2,0.5*s15}; Y[2][4][1] = Mono{2,0,0,-0.5*s15};

    static const int PL[15][3] = {{0,0,0},{0,1,1},{0,2,2},{1,0,1},{1,1,0},{1,1,1},{1,1,2},{1,2,1},
                                  {1,2,2},{2,0,2},{2,1,1},{2,1,2},{2,2,0},{2,2,1},{2,2,2}};
    static const int OFF[15]  = {0,1,10,35,44,53,80,125,170,245,270,315,390,415,490};
    static const int ANCH[15] = {0,0,0,0,0,5,22,22,29,0,22,9,0,13,2};
    const double ASGN[15] = {1,1,1,1,1, S111, 1,1, S122, 1,1, S212, 1, S221, S222};

    auto dfact = [](int n) { double r = 1.0; for (int k = n; k > 1; k -= 2) r *= k; return r; };

    // sym-traceless matrices for l=2 basis (for odd-parity invariants)
    double Mm[5][3][3]; memset(Mm, 0, sizeof(Mm));
    const double mh = s15 * 0.5;
    Mm[0][0][2] = Mm[0][2][0] = mh;          // xz
    Mm[1][0][1] = Mm[1][1][0] = mh;          // xy
    Mm[2][0][0] = -0.5*s5; Mm[2][1][1] = s5; Mm[2][2][2] = -0.5*s5;
    Mm[3][1][2] = Mm[3][2][1] = mh;          // yz
    Mm[4][0][0] = -mh; Mm[4][2][2] = mh;     // (z^2-x^2)/2 * sqrt15
    double T[3][5][5];
    for (int a = 0; a < 5; a++) for (int b = 0; b < 5; b++) {
        double K[3][3];
        for (int i = 0; i < 3; i++) for (int j = 0; j < 3; j++) {
            double ab = 0, ba = 0;
            for (int r = 0; r < 3; r++) { ab += Mm[a][i][r]*Mm[b][r][j]; ba += Mm[b][i][r]*Mm[a][r][j]; }
            K[i][j] = ab - ba;
        }
        T[0][a][b] = K[1][2]; T[1][a][b] = K[2][0]; T[2][a][b] = K[0][1];
    }

    for (int p = 0; p < 15; p++) {
        int l1 = PL[p][0], l2 = PL[p][1], l3 = PL[p][2];
        int d1 = 2*l1+1, d2 = 2*l2+1, d3 = 2*l3+1, d = d1*d2*d3;
        double tt[125];
        if (((l1 + l2 + l3) & 1) == 0) {
            // Gaunt: sphere-average of triple product of basis polynomials
            for (int i = 0; i < d1; i++) for (int j = 0; j < d2; j++) for (int k = 0; k < d3; k++) {
                double a = 0;
                for (int q1 = 0; q1 < nm[l1][i]; q1++)
                for (int q2 = 0; q2 < nm[l2][j]; q2++)
                for (int q3 = 0; q3 < nm[l3][k]; q3++) {
                    const Mono& A = Y[l1][i][q1]; const Mono& B = Y[l2][j][q2]; const Mono& C = Y[l3][k][q3];
                    int xa = A.a+B.a+C.a, yb = A.b+B.b+C.b, zc = A.c+B.c+C.c;
                    if ((xa & 1) || (yb & 1) || (zc & 1)) continue;
                    a += A.co*B.co*C.co * dfact(xa-1)*dfact(yb-1)*dfact(zc-1) / dfact(xa+yb+zc+1);
                }
                tt[(i*d2 + j)*d3 + k] = a;
            }
        } else if (p == 5) { // (1,1,1) = epsilon
            for (int q = 0; q < 27; q++) tt[q] = 0;
            tt[0*9+1*3+2] = 1; tt[1*9+2*3+0] = 1; tt[2*9+0*3+1] = 1;
            tt[0*9+2*3+1] = -1; tt[1*9+0*3+2] = -1; tt[2*9+1*3+0] = -1;
        } else {
            for (int q = 0; q < d; q++) tt[q] = 0;
            if (p == 8)  for (int i=0;i<3;i++) for(int a=0;a<5;a++) for(int b=0;b<5;b++) tt[(i*5+a)*5+b] = T[i][a][b];
            if (p == 11) for (int a=0;a<5;a++) for(int i=0;i<3;i++) for(int b=0;b<5;b++) tt[(a*3+i)*5+b] = T[i][a][b];
            if (p == 13) for (int a=0;a<5;a++) for(int b=0;b<5;b++) for(int i=0;i<3;i++) tt[(a*5+b)*3+i] = T[i][a][b];
        }
        double nrm = 0; for (int q = 0; q < d; q++) nrm += tt[q]*tt[q];
        nrm = sqrt(nrm);
        double sg = ((tt[ANCH[p]] >= 0) ? 1.0 : -1.0) * ASGN[p] / nrm;
        for (int q = 0; q < d; q++) w.v[OFF[p] + q] = (float)(tt[q] * sg);
    }
}

// ---------------- device tables ----------------
__device__ const int d_L1[15]    = {0,0,0,1,1,1,1,1,1,2,2,2,2,2,2};
__device__ const int d_L2[15]    = {0,1,2,0,1,1,1,2,2,0,1,1,2,2,2};
__device__ const int d_L3[15]    = {0,1,2,1,0,1,2,1,2,2,1,2,0,1,2};
__device__ const int d_OFF[15]   = {0,1,10,35,44,53,80,125,170,245,270,315,390,415,490};
__device__ const int d_CKOFF[15] = {0,1,4,9,18,21,30,45,54,69,94,109,134,139,154}; // prefix of d1*d3 (total 179)
__device__ const int d_SLO[3]    = {0,1,4};
__device__ const int d_PBYL3[15] = {0,4,12, 1,3,5,7,10,13, 2,6,8,9,11,14};
__device__ const int d_PL3S[4]   = {0,3,9,15};
__device__ const float d_INVNP[3] = {0.57735026918962584f, 0.40824829046386302f, 0.40824829046386302f};

// ---------------- kernels ----------------
__global__ void k_edge(const float* __restrict__ npos, float* __restrict__ sh, float* __restrict__ emb) {
    int e = blockIdx.x * blockDim.x + threadIdx.x;
    if (e >= E_EDGES) return;
    float vx = npos[e*6 + 0*2 + 1] - npos[e*6 + 0*2 + 0];
    float vy = npos[e*6 + 1*2 + 1] - npos[e*6 + 1*2 + 0];
    float vz = npos[e*6 + 2*2 + 1] - npos[e*6 + 2*2 + 0];
    float r = sqrtf(vx*vx + vy*vy + vz*vz);
    float inv = 1.0f / fmaxf(r, 1e-12f);
    float x = vx*inv, y = vy*inv, z = vz*inv;
    const float s3 = 1.7320508075688772f, s5 = 2.23606797749979f, s15 = 3.872983346207417f;
    sh[e*9+0] = 1.0f;
    sh[e*9+1] = s3*x; sh[e*9+2] = s3*y; sh[e*9+3] = s3*z;
    sh[e*9+4] = s15*x*z; sh[e*9+5] = s15*x*y;
    sh[e*9+6] = s5*(y*y - 0.5f*(x*x + z*z));
    sh[e*9+7] = s15*y*z;
    sh[e*9+8] = 0.5f*s15*(z*z - x*x);
    const float step = 4.0f / 11.0f;
    const float RC = (float)(1.14136 * 7.3890560989306495 * 3.1622776601683795); // 1.14136*e^2*sqrt(NB)
    for (int b = 0; b < 10; b++) {
        float center = step * (b + 1);
        float diff = (r - center) / step;
        float x1 = diff + 1.0f, x2 = 1.0f - diff;
        float u1 = (x1 > 0.0f) ? expf(-1.0f/x1) : 0.0f;
        float u2 = (x2 > 0.0f) ? expf(-1.0f/x2) : 0.0f;
        emb[e*10+b] = RC * u1 * u2;
    }
}

__global__ void k_init(const float* __restrict__ bar, const float* __restrict__ Wemb, float* __restrict__ x) {
    long long idx = (long long)blockIdx.x * blockDim.x + threadIdx.x;
    if (idx >= (long long)N_NODES * XSTR) return;
    int r = (int)(idx % XSTR);
    int n = (int)(idx / XSTR);
    int u = r / 9, m = r % 9;
    x[idx] = (m == 0) ? bar[n] * Wemb[u] : 0.0f;
}

__global__ __launch_bounds__(256) void k_layer(
    float* __restrict__ x, const float* __restrict__ sh_g, const float* __restrict__ emb_g,
    const float* __restrict__ Wsc, const float* __restrict__ Wlin1,
    const float* __restrict__ W1, const float* __restrict__ b1, const float* __restrict__ W2,
    const float* __restrict__ Wlin2, const float* __restrict__ Wg, W3J w3j)
{
    __shared__ float xs0[XSTR], xs1[XSTR], hbuf[XSTR], msg[XSTR], nw0[XSTR], nw1[XSTR];
    __shared__ float wls[750], t100[100], shs[9], embs[10], ck[179];
    __shared__ float sg0[50], sg1[50], gg0[50], gg1[50];
    const int e = blockIdx.x;
    const int t = threadIdx.x;
    const size_t b0 = (size_t)(2*e) * XSTR;
    const size_t b1o = (size_t)(2*e+1) * XSTR;

    for (int i = t; i < XSTR; i += 256) { xs0[i] = x[b0 + i]; xs1[i] = x[b1o + i]; }
    if (t < 9) shs[t] = sh_g[e*9 + t];
    if (t >= 32 && t < 42) embs[t-32] = emb_g[e*10 + (t-32)];
    __syncthreads();

    // radial MLP stage 1: t100 = gelu(emb@W1/sqrt(10) + b1)
    for (int j = t; j < 100; j += 256) {
        float a = 0;
        for (int b = 0; b < 10; b++) a += embs[b] * W1[b*100 + j];
        a = a * 0.31622776601683794f + b1[j];
        float th = tanhf(0.7978845608028654f * (a + 0.044715f * a*a*a));
        t100[j] = 0.5f * a * (1.0f + th);
    }
    __syncthreads();
    // stage 2: wls = (t100 @ W2)/10   (750 = MUL*15, o = u*15+p)
    for (int o = t; o < 750; o += 256) {
        float a = 0;
        for (int j = 0; j < 100; j++) a += t100[j] * W2[j*750 + o];
        wls[o] = a * 0.1f;
    }
    // h = lmix(x0,Wlin1)/sqrt50 ; nw0 = cs*lmix(x0,Wsc)/sqrt50 ; nw1 = cs*lmix(x1,Wsc)/sqrt50
    for (int idx = t; idx < 3*XSTR; idx += 256) {
        int which = idx / XSTR, r = idx % XSTR;
        int v = r / 9, m = r % 9;
        int l = (m == 0) ? 0 : ((m < 4) ? 1 : 2);
        const float* src = (which == 2) ? xs1 : xs0;
        const float* W = ((which == 0) ? Wlin1 : Wsc) + l*2500;
        float a = 0;
        for (int u = 0; u < MULC; u++) a += src[u*9 + m] * W[u*50 + v];
        if (which == 0) hbuf[r] = a * 0.1414213562373095f;              // 1/sqrt(50)
        else if (which == 1) nw0[r] = a * 0.13065629648763766f;         // cos(pi/8)/sqrt(50)
        else nw1[r] = a * 0.13065629648763766f;
    }
    __syncthreads();
    // ck[p][i][k] = sum_j C[i,j,k] * sh[j]
    for (int q = t; q < 179; q += 256) {
        int p = 0; while (p < 14 && q >= d_CKOFF[p+1]) p++;
        int rem = q - d_CKOFF[p];
        int D2 = 2*d_L2[p] + 1, D3 = 2*d_L3[p] + 1;
        int i = rem / D3, k = rem % D3;
        const float* C = w3j.v + d_OFF[p];
        const float* s = shs + d_SLO[d_L2[p]];
        float a = 0;
        for (int j = 0; j < D2; j++) a += C[(i*D2 + j)*D3 + k] * s[j];
        ck[q] = a;
    }
    __syncthreads();
    // msg[u][k] = sum_paths(l3) w[u,p]/sqrt(npath) * sum_i ck[p][i,kl] * h[u, off1+i]
    for (int idx = t; idx < XSTR; idx += 256) {
        int u = idx / 9, k = idx % 9;
        int l3 = (k == 0) ? 0 : ((k < 4) ? 1 : 2);
        int kl = k - d_SLO[l3];
        float a = 0;
        for (int pi = d_PL3S[l3]; pi < d_PL3S[l3+1]; pi++) {
            int p = d_PBYL3[pi];
            int D1 = 2*d_L1[p] + 1, D3 = 2*d_L3[p] + 1;
            const float* ckp = ck + d_CKOFF[p];
            const float* hp = hbuf + u*9 + d_SLO[d_L1[p]];
            float mm = 0;
            for (int i = 0; i < D1; i++) mm += ckp[i*D3 + kl] * hp[i];
            a += wls[u*15 + p] * mm;
        }
        msg[idx] = a * d_INVNP[l3];
    }
    __syncthreads();
    // nw1 += cx/(sqrt50*sqrt2) * lmix(msg, Wlin2)
    for (int idx = t; idx < XSTR; idx += 256) {
        int v = idx / 9, m = idx % 9;
        int l = (m == 0) ? 0 : ((m < 4) ? 1 : 2);
        const float* W = Wlin2 + l*2500;
        float a = 0;
        for (int u = 0; u < MULC; u++) a += msg[u*9 + m] * W[u*50 + v];
        nw1[idx] += a * 0.03826834323650898f;  // sin(pi/8)/10
    }
    __syncthreads();
    // gate
    if (t < 50) sg0[t] = nw0[t*9];
    else if (t >= 64 && t < 114) sg1[t-64] = nw1[(t-64)*9];
    __syncthreads();
    if (t < 50) {
        float a = 0;
        for (int u = 0; u < 50; u++) a += sg0[u] * Wg[u*50 + t];
        gg0[t] = 1.0f / (1.0f + expf(-a * 0.1414213562373095f));
    } else if (t >= 64 && t < 114) {
        int tt2 = t - 64;
        float a = 0;
        for (int u = 0; u < 50; u++) a += sg1[u] * Wg[u*50 + tt2];
        gg1[tt2] = 1.0f / (1.0f + expf(-a * 0.1414213562373095f));
    }
    __syncthreads();
    for (int idx = t; idx < XSTR; idx += 256) {
        int u = idx / 9, m = idx % 9;
        x[b0 + idx]  = (m == 0) ? sg0[u] * (1.0f/(1.0f + expf(-sg0[u]))) : nw0[idx] * gg0[u];
        x[b1o + idx] = (m == 0) ? sg1[u] * (1.0f/(1.0f + expf(-sg1[u]))) : nw1[idx] * gg1[u];
    }
}

__global__ void k_out(const float* __restrict__ x, const float* __restrict__ Wout, float* __restrict__ out) {
    int n = blockIdx.x * blockDim.x + threadIdx.x;
    if (n >= N_NODES) return;
    for (int m = 0; m < 3; m++) {
        float a = 0;
        for (int u = 0; u < MULC; u++) a += x[(size_t)n*XSTR + u*9 + 1 + m] * Wout[u];
        out[n*3 + m] = a * 0.1414213562373095f;
    }
}

// ---------------- launch ----------------
extern "C" void kernel_launch(void* const* d_in, const int* in_sizes, int n_in,
                              void* d_out, int out_size, void* d_ws, size_t ws_size,
                              hipStream_t stream) {
    const float* node_pos = (const float*)d_in[0];
    const float* bar      = (const float*)d_in[1];
    const float* Wemb     = (const float*)d_in[2];
    const float* Wsc      = (const float*)d_in[3];
    const float* Wlin1    = (const float*)d_in[4];
    const float* W1       = (const float*)d_in[5];
    const float* b1       = (const float*)d_in[6];
    const float* W2       = (const float*)d_in[7];
    const float* Wlin2    = (const float*)d_in[8];
    const float* Wgate    = (const float*)d_in[9];
    const float* Wout     = (const float*)d_in[10];
    float* out = (float*)d_out;

    float* sh  = (float*)d_ws;                  // E*9
    float* emb = sh + (size_t)E_EDGES*9;        // E*10
    float* x   = emb + (size_t)E_EDGES*10;      // N*450

    W3J w3j;
    build_w3j(w3j);

    k_edge<<<(E_EDGES + 255)/256, 256, 0, stream>>>(node_pos, sh, emb);
    k_init<<<(int)(((long long)N_NODES*XSTR + 255)/256), 256, 0, stream>>>(bar, Wemb, x);
    for (int l = 0; l < 3; l++) {
        k_layer<<<E_EDGES, 256, 0, stream>>>(x, sh, emb,
            Wsc + l*7500, Wlin1 + l*7500, W1 + l*1000, b1 + l*100,
            W2 + l*75000, Wlin2 + l*7500, Wgate + l*2500, w3j);
    }
    k_out<<<(N_NODES + 255)/256, 256, 0, stream>>>(x, Wout, out);
}

// Round 2
// 2946.271 us; speedup vs baseline: 2.9413x; 2.9413x over previous
//
#include <hip/hip_runtime.h>
#include <math.h>
#include <string.h>

// ---------------- problem constants ----------------
#define E_EDGES 40000
#define N_NODES 80000
#define MULC 50
#define XSTR 450      // MUL*9 per node
#define NE 5          // edges per block (weight-reuse blocking)

// ---- sign knobs (verified correct in round 1) ----
#define S111 1.0
#define S122 1.0
#define S212 1.0
#define S221 1.0
#define S222 1.0

struct W3J { float v[615]; };

// ---------------- host: build W3J tensors (verified round 1) ----------------
static void build_w3j(W3J& w) {
    const double s3 = sqrt(3.0), s5 = sqrt(5.0), s15 = sqrt(15.0);
    struct Mono { int a, b, c; double co; };
    Mono Y[3][5][3]; int nm[3][5];
    for (int l = 0; l < 3; l++) for (int c = 0; c < 5; c++) nm[l][c] = 0;
    nm[0][0] = 1; Y[0][0][0] = Mono{0,0,0,1.0};
    nm[1][0] = 1; Y[1][0][0] = Mono{1,0,0,s3};
    nm[1][1] = 1; Y[1][1][0] = Mono{0,1,0,s3};
    nm[1][2] = 1; Y[1][2][0] = Mono{0,0,1,s3};
    nm[2][0] = 1; Y[2][0][0] = Mono{1,0,1,s15};
    nm[2][1] = 1; Y[2][1][0] = Mono{1,1,0,s15};
    nm[2][2] = 3; Y[2][2][0] = Mono{0,2,0,s5};  Y[2][2][1] = Mono{2,0,0,-0.5*s5}; Y[2][2][2] = Mono{0,0,2,-0.5*s5};
    nm[2][3] = 1; Y[2][3][0] = Mono{0,1,1,s15};
    nm[2][4] = 2; Y[2][4][0] = Mono{0,0,2,0.5*s15}; Y[2][4][1] = Mono{2,0,0,-0.5*s15};

    static const int PL[15][3] = {{0,0,0},{0,1,1},{0,2,2},{1,0,1},{1,1,0},{1,1,1},{1,1,2},{1,2,1},
                                  {1,2,2},{2,0,2},{2,1,1},{2,1,2},{2,2,0},{2,2,1},{2,2,2}};
    static const int OFF[15]  = {0,1,10,35,44,53,80,125,170,245,270,315,390,415,490};
    static const int ANCH[15] = {0,0,0,0,0,5,22,22,29,0,22,9,0,13,2};
    const double ASGN[15] = {1,1,1,1,1, S111, 1,1, S122, 1,1, S212, 1, S221, S222};

    auto dfact = [](int n) { double r = 1.0; for (int k = n; k > 1; k -= 2) r *= k; return r; };

    double Mm[5][3][3]; memset(Mm, 0, sizeof(Mm));
    const double mh = s15 * 0.5;
    Mm[0][0][2] = Mm[0][2][0] = mh;
    Mm[1][0][1] = Mm[1][1][0] = mh;
    Mm[2][0][0] = -0.5*s5; Mm[2][1][1] = s5; Mm[2][2][2] = -0.5*s5;
    Mm[3][1][2] = Mm[3][2][1] = mh;
    Mm[4][0][0] = -mh; Mm[4][2][2] = mh;
    double T[3][5][5];
    for (int a = 0; a < 5; a++) for (int b = 0; b < 5; b++) {
        double K[3][3];
        for (int i = 0; i < 3; i++) for (int j = 0; j < 3; j++) {
            double ab = 0, ba = 0;
            for (int r = 0; r < 3; r++) { ab += Mm[a][i][r]*Mm[b][r][j]; ba += Mm[b][i][r]*Mm[a][r][j]; }
            K[i][j] = ab - ba;
        }
        T[0][a][b] = K[1][2]; T[1][a][b] = K[2][0]; T[2][a][b] = K[0][1];
    }

    for (int p = 0; p < 15; p++) {
        int l1 = PL[p][0], l2 = PL[p][1], l3 = PL[p][2];
        int d1 = 2*l1+1, d2 = 2*l2+1, d3 = 2*l3+1, d = d1*d2*d3;
        double tt[125];
        if (((l1 + l2 + l3) & 1) == 0) {
            for (int i = 0; i < d1; i++) for (int j = 0; j < d2; j++) for (int k = 0; k < d3; k++) {
                double a = 0;
                for (int q1 = 0; q1 < nm[l1][i]; q1++)
                for (int q2 = 0; q2 < nm[l2][j]; q2++)
                for (int q3 = 0; q3 < nm[l3][k]; q3++) {
                    const Mono& A = Y[l1][i][q1]; const Mono& B = Y[l2][j][q2]; const Mono& C = Y[l3][k][q3];
                    int xa = A.a+B.a+C.a, yb = A.b+B.b+C.b, zc = A.c+B.c+C.c;
                    if ((xa & 1) || (yb & 1) || (zc & 1)) continue;
                    a += A.co*B.co*C.co * dfact(xa-1)*dfact(yb-1)*dfact(zc-1) / dfact(xa+yb+zc+1);
                }
                tt[(i*d2 + j)*d3 + k] = a;
            }
        } else if (p == 5) {
            for (int q = 0; q < 27; q++) tt[q] = 0;
            tt[0*9+1*3+2] = 1; tt[1*9+2*3+0] = 1; tt[2*9+0*3+1] = 1;
            tt[0*9+2*3+1] = -1; tt[1*9+0*3+2] = -1; tt[2*9+1*3+0] = -1;
        } else {
            for (int q = 0; q < d; q++) tt[q] = 0;
            if (p == 8)  for (int i=0;i<3;i++) for(int a=0;a<5;a++) for(int b=0;b<5;b++) tt[(i*5+a)*5+b] = T[i][a][b];
            if (p == 11) for (int a=0;a<5;a++) for(int i=0;i<3;i++) for(int b=0;b<5;b++) tt[(a*3+i)*5+b] = T[i][a][b];
            if (p == 13) for (int a=0;a<5;a++) for(int b=0;b<5;b++) for(int i=0;i<3;i++) tt[(a*5+b)*3+i] = T[i][a][b];
        }
        double nrm = 0; for (int q = 0; q < d; q++) nrm += tt[q]*tt[q];
        nrm = sqrt(nrm);
        double sg = ((tt[ANCH[p]] >= 0) ? 1.0 : -1.0) * ASGN[p] / nrm;
        for (int q = 0; q < d; q++) w.v[OFF[p] + q] = (float)(tt[q] * sg);
    }
}

// ---------------- device tables ----------------
__device__ const int d_L1[15]    = {0,0,0,1,1,1,1,1,1,2,2,2,2,2,2};
__device__ const int d_L2[15]    = {0,1,2,0,1,1,1,2,2,0,1,1,2,2,2};
__device__ const int d_L3[15]    = {0,1,2,1,0,1,2,1,2,2,1,2,0,1,2};
__device__ const int d_OFF[15]   = {0,1,10,35,44,53,80,125,170,245,270,315,390,415,490};
__device__ const int d_CKOFF[15] = {0,1,4,9,18,21,30,45,54,69,94,109,134,139,154};
__device__ const int d_SLO[3]    = {0,1,4};
__device__ const int d_PBYL3[15] = {0,4,12, 1,3,5,7,10,13, 2,6,8,9,11,14};
__device__ const int d_PL3S[4]   = {0,3,9,15};
__device__ const float d_INVNP[3] = {0.57735026918962584f, 0.40824829046386302f, 0.40824829046386302f};

#define S_H  0.1414213562373095f    // 1/sqrt(50)
#define S_CS 0.13065629648763766f   // cos(pi/8)/sqrt(50)
#define S_L2 0.03826834323650898f   // sin(pi/8)/10

// ---------------- kernels ----------------
__global__ void k_edge(const float* __restrict__ npos, float* __restrict__ sh, float* __restrict__ emb) {
    int e = blockIdx.x * blockDim.x + threadIdx.x;
    if (e >= E_EDGES) return;
    float vx = npos[e*6 + 0*2 + 1] - npos[e*6 + 0*2 + 0];
    float vy = npos[e*6 + 1*2 + 1] - npos[e*6 + 1*2 + 0];
    float vz = npos[e*6 + 2*2 + 1] - npos[e*6 + 2*2 + 0];
    float r = sqrtf(vx*vx + vy*vy + vz*vz);
    float inv = 1.0f / fmaxf(r, 1e-12f);
    float x = vx*inv, y = vy*inv, z = vz*inv;
    const float s3 = 1.7320508075688772f, s5 = 2.23606797749979f, s15 = 3.872983346207417f;
    sh[e*9+0] = 1.0f;
    sh[e*9+1] = s3*x; sh[e*9+2] = s3*y; sh[e*9+3] = s3*z;
    sh[e*9+4] = s15*x*z; sh[e*9+5] = s15*x*y;
    sh[e*9+6] = s5*(y*y - 0.5f*(x*x + z*z));
    sh[e*9+7] = s15*y*z;
    sh[e*9+8] = 0.5f*s15*(z*z - x*x);
    const float step = 4.0f / 11.0f;
    const float RC = (float)(1.14136 * 7.3890560989306495 * 3.1622776601683795);
    for (int b = 0; b < 10; b++) {
        float center = step * (b + 1);
        float diff = (r - center) / step;
        float x1 = diff + 1.0f, x2 = 1.0f - diff;
        float u1 = (x1 > 0.0f) ? expf(-1.0f/x1) : 0.0f;
        float u2 = (x2 > 0.0f) ? expf(-1.0f/x2) : 0.0f;
        emb[e*10+b] = RC * u1 * u2;
    }
}

__global__ void k_init(const float* __restrict__ bar, const float* __restrict__ Wemb, float* __restrict__ x) {
    long long idx = (long long)blockIdx.x * blockDim.x + threadIdx.x;
    if (idx >= (long long)N_NODES * XSTR) return;
    int r = (int)(idx % XSTR);
    int n = (int)(idx / XSTR);
    int u = r / 9, m = r % 9;
    x[idx] = (m == 0) ? bar[n] * Wemb[u] : 0.0f;
}

__device__ __forceinline__ float sigf(float a) { return 1.0f / (1.0f + expf(-a)); }

__global__ __launch_bounds__(256, 2) void k_layer(
    float* __restrict__ x, const float* __restrict__ sh_g, const float* __restrict__ emb_g,
    const float* __restrict__ Wsc, const float* __restrict__ Wlin1,
    const float* __restrict__ W1, const float* __restrict__ b1, const float* __restrict__ W2,
    const float* __restrict__ Wlin2, const float* __restrict__ Wg, W3J w3j)
{
    __shared__ float xs0[NE][450], xs1[NE][450], hbuf[NE][450], msg[NE][450];
    __shared__ float wls[NE][750], t100[NE][100];
    __shared__ float shs[NE][9], embs[NE][10], ck[NE][180];
    __shared__ float gg0[NE][50], gg1[NE][50];
    const int t = threadIdx.x;
    const int e0 = blockIdx.x * NE;

    // ---- P0: load node features + per-edge sh/emb ----
    for (int idx = t; idx < NE*450; idx += 256) {
        int e = idx / 450, i = idx % 450;
        xs0[e][i] = x[(size_t)(2*(e0+e))   * 450 + i];
        xs1[e][i] = x[(size_t)(2*(e0+e)+1) * 450 + i];
    }
    if (t < NE*9)  shs[t/9][t%9] = sh_g[(size_t)(e0 + t/9)*9 + t%9];
    if (t >= 64 && t < 64 + NE*10) { int q = t - 64; embs[q/10][q%10] = emb_g[(size_t)(e0 + q/10)*10 + q%10]; }
    __syncthreads();

    // ---- P1: radial stage 1 (t100) + ck = C contracted with sh ----
    for (int idx = t; idx < NE*100; idx += 256) {
        int e = idx / 100, j = idx % 100;
        float a = 0;
        #pragma unroll
        for (int b = 0; b < 10; b++) a += embs[e][b] * W1[b*100 + j];
        a = a * 0.31622776601683794f + b1[j];
        float th = tanhf(0.7978845608028654f * (a + 0.044715f * a*a*a));
        t100[e][j] = 0.5f * a * (1.0f + th);
    }
    for (int idx = t; idx < NE*180; idx += 256) {
        int e = idx / 180, q = idx % 180;
        if (q < 179) {
            int p = 0; while (p < 14 && q >= d_CKOFF[p+1]) p++;
            int rem = q - d_CKOFF[p];
            int D2 = 2*d_L2[p] + 1, D3 = 2*d_L3[p] + 1;
            int i = rem / D3, k = rem % D3;
            const float* C = w3j.v + d_OFF[p];
            const float* s = &shs[e][d_SLO[d_L2[p]]];
            float a = 0;
            for (int j = 0; j < D2; j++) a += C[(i*D2 + j)*D3 + k] * s[j];
            ck[e][q] = a;
        }
    }
    __syncthreads();

    // ---- P2: radial stage 2  wls[e][o] = (t100[e] @ W2[:,o]) / 10 ----
    {
        const int o0 = t, o1 = t + 256;
        const bool has2 = (t < 750 - 512);
        const int o2 = has2 ? (t + 512) : 749;
        float a0[NE], a1[NE], a2[NE];
        #pragma unroll
        for (int e = 0; e < NE; e++) { a0[e] = 0; a1[e] = 0; a2[e] = 0; }
        #pragma unroll 2
        for (int j = 0; j < 100; j++) {
            const float* W2j = W2 + j*750;
            float w0 = W2j[o0], w1 = W2j[o1], w2 = W2j[o2];
            #pragma unroll
            for (int e = 0; e < NE; e++) {
                float tv = t100[e][j];
                a0[e] += w0 * tv; a1[e] += w1 * tv; a2[e] += w2 * tv;
            }
        }
        #pragma unroll
        for (int e = 0; e < NE; e++) {
            wls[e][o0] = a0[e] * 0.1f;
            wls[e][o1] = a1[e] * 0.1f;
            if (has2) wls[e][o2] = a2[e] * 0.1f;
        }
    }

    // ---- P3 compute: three lmixes into registers (thread owns (v,e), all 9 m) ----
    float hh[9], n0r[9], n1r[9];
    #pragma unroll
    for (int m = 0; m < 9; m++) { hh[m] = 0; n0r[m] = 0; n1r[m] = 0; }
    const bool act = (t < 50*NE);
    const int v = t / NE, ea = t % NE;
    if (act) {
        #pragma unroll 2
        for (int u = 0; u < 50; u++) {
            float wl[3], ws[3];
            #pragma unroll
            for (int l = 0; l < 3; l++) {
                wl[l] = Wlin1[l*2500 + u*50 + v];
                ws[l] = Wsc  [l*2500 + u*50 + v];
            }
            const float* x0p = &xs0[ea][u*9];
            const float* x1p = &xs1[ea][u*9];
            #pragma unroll
            for (int m = 0; m < 9; m++) {
                int l = (m == 0) ? 0 : ((m < 4) ? 1 : 2);
                float a = x0p[m], b = x1p[m];
                hh[m]  += a * wl[l];
                n0r[m] += a * ws[l];
                n1r[m] += b * ws[l];
            }
        }
    }
    __syncthreads();   // all xs reads done, wls visible
    if (act) {
        #pragma unroll
        for (int m = 0; m < 9; m++) {
            hbuf[ea][v*9 + m] = hh[m]  * S_H;
            xs0 [ea][v*9 + m] = n0r[m] * S_CS;   // nw0 overwrites xs0
            xs1 [ea][v*9 + m] = n1r[m] * S_CS;   // nw1 overwrites xs1
        }
    }
    __syncthreads();

    // ---- P5: tensor-product messages ----
    for (int idx = t; idx < NE*450; idx += 256) {
        int e = idx / 450, r = idx % 450;
        int u = r / 9, k = r % 9;
        int l3 = (k == 0) ? 0 : ((k < 4) ? 1 : 2);
        int kl = k - d_SLO[l3];
        float a = 0;
        for (int pi = d_PL3S[l3]; pi < d_PL3S[l3+1]; pi++) {
            int p = d_PBYL3[pi];
            int D1 = 2*d_L1[p] + 1, D3 = 2*d_L3[p] + 1;
            const float* ckp = &ck[e][d_CKOFF[p]];
            const float* hp  = &hbuf[e][u*9 + d_SLO[d_L1[p]]];
            float mm = 0;
            for (int i = 0; i < D1; i++) mm += ckp[i*D3 + kl] * hp[i];
            a += wls[e][u*15 + p] * mm;
        }
        msg[e][r] = a * d_INVNP[l3];
    }
    __syncthreads();

    // ---- P6: nw1 += lmix(msg, Wlin2) * S_L2 ----
    if (act) {
        float am[9];
        #pragma unroll
        for (int m = 0; m < 9; m++) am[m] = 0;
        #pragma unroll 2
        for (int u = 0; u < 50; u++) {
            float wl[3];
            #pragma unroll
            for (int l = 0; l < 3; l++) wl[l] = Wlin2[l*2500 + u*50 + v];
            const float* mp = &msg[ea][u*9];
            #pragma unroll
            for (int m = 0; m < 9; m++) {
                int l = (m == 0) ? 0 : ((m < 4) ? 1 : 2);
                am[m] += mp[m] * wl[l];
            }
        }
        #pragma unroll
        for (int m = 0; m < 9; m++) xs1[ea][v*9 + m] += am[m] * S_L2;
    }
    __syncthreads();

    // ---- P7: gate matmuls ----
    if (act) {
        float a0 = 0, a1 = 0;
        #pragma unroll 2
        for (int u = 0; u < 50; u++) {
            float wg = Wg[u*50 + v];
            a0 += xs0[ea][u*9] * wg;
            a1 += xs1[ea][u*9] * wg;
        }
        gg0[ea][v] = sigf(a0 * S_H);
        gg1[ea][v] = sigf(a1 * S_H);
    }
    __syncthreads();

    // ---- P8: gate apply + writeback ----
    for (int idx = t; idx < NE*450; idx += 256) {
        int e = idx / 450, i = idx % 450;
        int u = i / 9, m = i % 9;
        float v0 = xs0[e][i], v1 = xs1[e][i];
        x[(size_t)(2*(e0+e))   * 450 + i] = (m == 0) ? v0 * sigf(v0) : v0 * gg0[e][u];
        x[(size_t)(2*(e0+e)+1) * 450 + i] = (m == 0) ? v1 * sigf(v1) : v1 * gg1[e][u];
    }
}

__global__ void k_out(const float* __restrict__ x, const float* __restrict__ Wout, float* __restrict__ out) {
    int n = blockIdx.x * blockDim.x + threadIdx.x;
    if (n >= N_NODES) return;
    for (int m = 0; m < 3; m++) {
        float a = 0;
        for (int u = 0; u < MULC; u++) a += x[(size_t)n*XSTR + u*9 + 1 + m] * Wout[u];
        out[n*3 + m] = a * S_H;
    }
}

// ---------------- launch ----------------
extern "C" void kernel_launch(void* const* d_in, const int* in_sizes, int n_in,
                              void* d_out, int out_size, void* d_ws, size_t ws_size,
                              hipStream_t stream) {
    const float* node_pos = (const float*)d_in[0];
    const float* bar      = (const float*)d_in[1];
    const float* Wemb     = (const float*)d_in[2];
    const float* Wsc      = (const float*)d_in[3];
    const float* Wlin1    = (const float*)d_in[4];
    const float* W1       = (const float*)d_in[5];
    const float* b1       = (const float*)d_in[6];
    const float* W2       = (const float*)d_in[7];
    const float* Wlin2    = (const float*)d_in[8];
    const float* Wgate    = (const float*)d_in[9];
    const float* Wout     = (const float*)d_in[10];
    float* out = (float*)d_out;

    float* sh  = (float*)d_ws;                  // E*9
    float* emb = sh + (size_t)E_EDGES*9;        // E*10
    float* x   = emb + (size_t)E_EDGES*10;      // N*450

    W3J w3j;
    build_w3j(w3j);

    k_edge<<<(E_EDGES + 255)/256, 256, 0, stream>>>(node_pos, sh, emb);
    k_init<<<(int)(((long long)N_NODES*XSTR + 255)/256), 256, 0, stream>>>(bar, Wemb, x);
    for (int l = 0; l < 3; l++) {
        k_layer<<<E_EDGES/NE, 256, 0, stream>>>(x, sh, emb,
            Wsc + l*7500, Wlin1 + l*7500, W1 + l*1000, b1 + l*100,
            W2 + l*75000, Wlin2 + l*7500, Wgate + l*2500, w3j);
    }
    k_out<<<(N_NODES + 255)/256, 256, 0, stream>>>(x, Wout, out);
}

// Round 3
// 1205.540 us; speedup vs baseline: 7.1883x; 2.4439x over previous
//
#include <hip/hip_runtime.h>
#include <math.h>
#include <string.h>

// ---------------- problem constants ----------------
#define E_EDGES 40000
#define N_NODES 80000
#define NE 4          // edges per block

// ---- sign knobs (verified correct in round 1) ----
#define S111 1.0
#define S122 1.0
#define S212 1.0
#define S221 1.0
#define S222 1.0

struct W3J { float v[615]; };

// ---------------- host: build W3J tensors (verified round 1) ----------------
static void build_w3j(W3J& w) {
    const double s3 = sqrt(3.0), s5 = sqrt(5.0), s15 = sqrt(15.0);
    struct Mono { int a, b, c; double co; };
    Mono Y[3][5][3]; int nm[3][5];
    for (int l = 0; l < 3; l++) for (int c = 0; c < 5; c++) nm[l][c] = 0;
    nm[0][0] = 1; Y[0][0][0] = Mono{0,0,0,1.0};
    nm[1][0] = 1; Y[1][0][0] = Mono{1,0,0,s3};
    nm[1][1] = 1; Y[1][1][0] = Mono{0,1,0,s3};
    nm[1][2] = 1; Y[1][2][0] = Mono{0,0,1,s3};
    nm[2][0] = 1; Y[2][0][0] = Mono{1,0,1,s15};
    nm[2][1] = 1; Y[2][1][0] = Mono{1,1,0,s15};
    nm[2][2] = 3; Y[2][2][0] = Mono{0,2,0,s5};  Y[2][2][1] = Mono{2,0,0,-0.5*s5}; Y[2][2][2] = Mono{0,0,2,-0.5*s5};
    nm[2][3] = 1; Y[2][3][0] = Mono{0,1,1,s15};
    nm[2][4] = 2; Y[2][4][0] = Mono{0,0,2,0.5*s15}; Y[2][4][1] = Mono{2,0,0,-0.5*s15};

    static const int PL[15][3] = {{0,0,0},{0,1,1},{0,2,2},{1,0,1},{1,1,0},{1,1,1},{1,1,2},{1,2,1},
                                  {1,2,2},{2,0,2},{2,1,1},{2,1,2},{2,2,0},{2,2,1},{2,2,2}};
    static const int OFF[15]  = {0,1,10,35,44,53,80,125,170,245,270,315,390,415,490};
    static const int ANCH[15] = {0,0,0,0,0,5,22,22,29,0,22,9,0,13,2};
    const double ASGN[15] = {1,1,1,1,1, S111, 1,1, S122, 1,1, S212, 1, S221, S222};

    auto dfact = [](int n) { double r = 1.0; for (int k = n; k > 1; k -= 2) r *= k; return r; };

    double Mm[5][3][3]; memset(Mm, 0, sizeof(Mm));
    const double mh = s15 * 0.5;
    Mm[0][0][2] = Mm[0][2][0] = mh;
    Mm[1][0][1] = Mm[1][1][0] = mh;
    Mm[2][0][0] = -0.5*s5; Mm[2][1][1] = s5; Mm[2][2][2] = -0.5*s5;
    Mm[3][1][2] = Mm[3][2][1] = mh;
    Mm[4][0][0] = -mh; Mm[4][2][2] = mh;
    double T[3][5][5];
    for (int a = 0; a < 5; a++) for (int b = 0; b < 5; b++) {
        double K[3][3];
        for (int i = 0; i < 3; i++) for (int j = 0; j < 3; j++) {
            double ab = 0, ba = 0;
            for (int r = 0; r < 3; r++) { ab += Mm[a][i][r]*Mm[b][r][j]; ba += Mm[b][i][r]*Mm[a][r][j]; }
            K[i][j] = ab - ba;
        }
        T[0][a][b] = K[1][2]; T[1][a][b] = K[2][0]; T[2][a][b] = K[0][1];
    }

    for (int p = 0; p < 15; p++) {
        int l1 = PL[p][0], l2 = PL[p][1], l3 = PL[p][2];
        int d1 = 2*l1+1, d2 = 2*l2+1, d3 = 2*l3+1, d = d1*d2*d3;
        double tt[125];
        if (((l1 + l2 + l3) & 1) == 0) {
            for (int i = 0; i < d1; i++) for (int j = 0; j < d2; j++) for (int k = 0; k < d3; k++) {
                double a = 0;
                for (int q1 = 0; q1 < nm[l1][i]; q1++)
                for (int q2 = 0; q2 < nm[l2][j]; q2++)
                for (int q3 = 0; q3 < nm[l3][k]; q3++) {
                    const Mono& A = Y[l1][i][q1]; const Mono& B = Y[l2][j][q2]; const Mono& C = Y[l3][k][q3];
                    int xa = A.a+B.a+C.a, yb = A.b+B.b+C.b, zc = A.c+B.c+C.c;
                    if ((xa & 1) || (yb & 1) || (zc & 1)) continue;
                    a += A.co*B.co*C.co * dfact(xa-1)*dfact(yb-1)*dfact(zc-1) / dfact(xa+yb+zc+1);
                }
                tt[(i*d2 + j)*d3 + k] = a;
            }
        } else if (p == 5) {
            for (int q = 0; q < 27; q++) tt[q] = 0;
            tt[0*9+1*3+2] = 1; tt[1*9+2*3+0] = 1; tt[2*9+0*3+1] = 1;
            tt[0*9+2*3+1] = -1; tt[1*9+0*3+2] = -1; tt[2*9+1*3+0] = -1;
        } else {
            for (int q = 0; q < d; q++) tt[q] = 0;
            if (p == 8)  for (int i=0;i<3;i++) for(int a=0;a<5;a++) for(int b=0;b<5;b++) tt[(i*5+a)*5+b] = T[i][a][b];
            if (p == 11) for (int a=0;a<5;a++) for(int i=0;i<3;i++) for(int b=0;b<5;b++) tt[(a*3+i)*5+b] = T[i][a][b];
            if (p == 13) for (int a=0;a<5;a++) for(int b=0;b<5;b++) for(int i=0;i<3;i++) tt[(a*5+b)*3+i] = T[i][a][b];
        }
        double nrm = 0; for (int q = 0; q < d; q++) nrm += tt[q]*tt[q];
        nrm = sqrt(nrm);
        double sg = ((tt[ANCH[p]] >= 0) ? 1.0 : -1.0) * ASGN[p] / nrm;
        for (int q = 0; q < d; q++) w.v[OFF[p] + q] = (float)(tt[q] * sg);
    }
}

// ---------------- device tables (runtime-indexed, for the ck phase) ----------------
__device__ const int d_L2r[15]    = {0,1,2,0,1,1,1,2,2,0,1,1,2,2,2};
__device__ const int d_L3r[15]    = {0,1,2,1,0,1,2,1,2,2,1,2,0,1,2};
__device__ const int d_OFFr[15]   = {0,1,10,35,44,53,80,125,170,245,270,315,390,415,490};
__device__ const int d_CKOFFr[15] = {0,1,4,9,18,21,30,45,54,69,94,109,134,139,154};
__device__ const int d_SLOr[3]    = {0,1,4};

#define S_H  0.1414213562373095f    // 1/sqrt(50)
#define S_CS 0.13065629648763766f   // cos(pi/8)/sqrt(50)
#define S_L2 0.03826834323650898f   // sin(pi/8)/10

__device__ __forceinline__ float sigf(float a) { return 1.0f / (1.0f + expf(-a)); }

// ---------------- the fused 3-layer kernel ----------------
// Node pairs (2e, 2e+1) are independent through ALL layers (src=2e, dst=2e+1,
// gate is per-node) -> entire network runs in LDS, no global x buffer.
__global__ __launch_bounds__(256, 4) void k_fused(
    const float* __restrict__ node_pos, const float* __restrict__ bar,
    const float* __restrict__ Wemb, const float* __restrict__ Wsc,
    const float* __restrict__ Wlin1, const float* __restrict__ W1,
    const float* __restrict__ b1, const float* __restrict__ W2,
    const float* __restrict__ Wlin2, const float* __restrict__ Wgate,
    const float* __restrict__ Wout, float* __restrict__ out, W3J w3j)
{
    // 38.4 KB -> 4 blocks/CU (16 waves/CU)
    __shared__ float xs0[NE][450], xs1[NE][450], msg[NE][450];
    __shared__ float wls[NE][750];
    __shared__ float tgg[NE][100];   // union: t100 (P1->P2) / gates (P7->P8)
    __shared__ float shs[NE][9], embs[NE][10], ck[NE][180];
    __shared__ float barr[NE][2];

    const int t = threadIdx.x;
    const int e0 = blockIdx.x * NE;

    // compile-time path tables (P5 is fully unrolled -> static register indices)
    constexpr int cL1[15]    = {0,0,0,1,1,1,1,1,1,2,2,2,2,2,2};
    constexpr int cCKOFF[15] = {0,1,4,9,18,21,30,45,54,69,94,109,134,139,154};
    constexpr int cSLO[3]    = {0,1,4};
    constexpr int cPBYL3[15] = {0,4,12, 1,3,5,7,10,13, 2,6,8,9,11,14};
    constexpr int cPL3S[4]   = {0,3,9,15};
    constexpr float cINVNP[3] = {0.57735026918962584f, 0.40824829046386302f, 0.40824829046386302f};

    // ---- Phase A: per-edge sh + radial embedding (computed inline) ----
    if (t < NE) {
        const int e = t;
        const float* np = node_pos + (size_t)(e0 + e) * 6;
        float vx = np[1] - np[0], vy = np[3] - np[2], vz = np[5] - np[4];
        float r = sqrtf(vx*vx + vy*vy + vz*vz);
        float inv = 1.0f / fmaxf(r, 1e-12f);
        float x = vx*inv, y = vy*inv, z = vz*inv;
        const float s3 = 1.7320508075688772f, s5 = 2.23606797749979f, s15 = 3.872983346207417f;
        shs[e][0] = 1.0f;
        shs[e][1] = s3*x; shs[e][2] = s3*y; shs[e][3] = s3*z;
        shs[e][4] = s15*x*z; shs[e][5] = s15*x*y;
        shs[e][6] = s5*(y*y - 0.5f*(x*x + z*z));
        shs[e][7] = s15*y*z;
        shs[e][8] = 0.5f*s15*(z*z - x*x);
        const float step = 4.0f / 11.0f;
        const float RC = (float)(1.14136 * 7.3890560989306495 * 3.1622776601683795);
        #pragma unroll
        for (int b = 0; b < 10; b++) {
            float center = step * (b + 1);
            float diff = (r - center) / step;
            float x1 = diff + 1.0f, x2 = 1.0f - diff;
            float u1 = (x1 > 0.0f) ? expf(-1.0f/x1) : 0.0f;
            float u2 = (x2 > 0.0f) ? expf(-1.0f/x2) : 0.0f;
            embs[e][b] = RC * u1 * u2;
        }
    }
    if (t >= 64 && t < 64 + 2*NE) {
        int q = t - 64;
        barr[q >> 1][q & 1] = bar[2*e0 + q];
    }
    __syncthreads();

    // ---- Phase B: ck[p][i][k] = sum_j C[i,j,k]*sh[j] (layer-invariant) + x init ----
    for (int idx = t; idx < NE*179; idx += 256) {
        int e = idx / 179, q = idx % 179;
        int p = 0; while (p < 14 && q >= d_CKOFFr[p+1]) p++;
        int rem = q - d_CKOFFr[p];
        int D2 = 2*d_L2r[p] + 1, D3 = 2*d_L3r[p] + 1;
        int i = rem / D3, k = rem % D3;
        const float* C = w3j.v + d_OFFr[p];
        const float* s = &shs[e][d_SLOr[d_L2r[p]]];
        float a = 0;
        for (int j = 0; j < D2; j++) a += C[(i*D2 + j)*D3 + k] * s[j];
        ck[e][q] = a;
    }
    for (int idx = t; idx < 2*NE*450; idx += 256) {
        int n = idx / 450, i = idx % 450;
        int e = n >> 1, half = n & 1;
        int u = i / 9, m = i % 9;
        float val = (m == 0) ? barr[e][half] * Wemb[u] : 0.0f;
        if (half) xs1[e][i] = val; else xs0[e][i] = val;
    }
    __syncthreads();

    const bool act = (t < 50*NE);
    const int v = t / NE, ea = t % NE;

    // ================== 3 layers, all in LDS ==================
    for (int L = 0; L < 3; L++) {
        const float* W1L    = W1    + L*1000;
        const float* b1L    = b1    + L*100;
        const float* W2L    = W2    + L*75000;
        const float* WscL   = Wsc   + L*7500;
        const float* Wlin1L = Wlin1 + L*7500;
        const float* Wlin2L = Wlin2 + L*7500;
        const float* WgL    = Wgate + L*2500;

        // ---- P1: t100 = gelu(emb@W1/sqrt(10) + b1) ----
        for (int idx = t; idx < NE*100; idx += 256) {
            int e = idx / 100, j = idx % 100;
            float a = 0;
            #pragma unroll
            for (int b = 0; b < 10; b++) a += embs[e][b] * W1L[b*100 + j];
            a = a * 0.31622776601683794f + b1L[j];
            float th = tanhf(0.7978845608028654f * (a + 0.044715f * a*a*a));
            tgg[e][j] = 0.5f * a * (1.0f + th);
        }
        __syncthreads();

        // ---- P2: wls = (t100 @ W2)/10 (no barrier here; covered by P3's) ----
        {
            const int o0 = t, o1 = t + 256;
            const bool has2 = (t < 750 - 512);
            const int o2 = has2 ? (t + 512) : 749;
            float a0[NE], a1[NE], a2[NE];
            #pragma unroll
            for (int e = 0; e < NE; e++) { a0[e] = 0; a1[e] = 0; a2[e] = 0; }
            #pragma unroll 4
            for (int j = 0; j < 100; j++) {
                const float* W2j = W2L + j*750;
                float w0 = W2j[o0], w1 = W2j[o1], w2 = W2j[o2];
                #pragma unroll
                for (int e = 0; e < NE; e++) {
                    float tv = tgg[e][j];
                    a0[e] += w0 * tv; a1[e] += w1 * tv; a2[e] += w2 * tv;
                }
            }
            #pragma unroll
            for (int e = 0; e < NE; e++) {
                wls[e][o0] = a0[e] * 0.1f;
                wls[e][o1] = a1[e] * 0.1f;
                if (has2) wls[e][o2] = a2[e] * 0.1f;
            }
        }

        // ---- P3: three lmixes; h stays in registers (thread owns (v,ea)) ----
        float hsc[9], n0r[9], n1r[9];
        #pragma unroll
        for (int m = 0; m < 9; m++) { hsc[m] = 0; n0r[m] = 0; n1r[m] = 0; }
        if (act) {
            #pragma unroll 2
            for (int u = 0; u < 50; u++) {
                float wl[3], ws[3];
                #pragma unroll
                for (int l = 0; l < 3; l++) {
                    wl[l] = Wlin1L[l*2500 + u*50 + v];
                    ws[l] = WscL  [l*2500 + u*50 + v];
                }
                const float* x0p = &xs0[ea][u*9];
                const float* x1p = &xs1[ea][u*9];
                #pragma unroll
                for (int m = 0; m < 9; m++) {
                    int l = (m == 0) ? 0 : ((m < 4) ? 1 : 2);
                    float a = x0p[m], b = x1p[m];
                    hsc[m] += a * wl[l];
                    n0r[m] += a * ws[l];
                    n1r[m] += b * ws[l];
                }
            }
        }
        __syncthreads();   // xs reads done; wls/t100 settled
        if (act) {
            #pragma unroll
            for (int m = 0; m < 9; m++) {
                hsc[m] *= S_H;
                xs0[ea][v*9 + m] = n0r[m] * S_CS;
                xs1[ea][v*9 + m] = n1r[m] * S_CS;
            }
        }
        __syncthreads();

        // ---- P5: tensor-product messages (fully unrolled, h from registers) ----
        if (act) {
            #pragma unroll
            for (int k = 0; k < 9; ++k) {
                const int l3 = (k == 0) ? 0 : ((k < 4) ? 1 : 2);
                const int kl = k - cSLO[l3];
                float a = 0.f;
                #pragma unroll
                for (int pi = cPL3S[l3]; pi < cPL3S[l3+1]; ++pi) {
                    const int p = cPBYL3[pi];
                    const int l1 = cL1[p];
                    const int D1 = 2*l1 + 1, D3 = 2*l3 + 1;
                    float mm = 0.f;
                    #pragma unroll
                    for (int i = 0; i < D1; ++i)
                        mm += ck[ea][cCKOFF[p] + i*D3 + kl] * hsc[cSLO[l1] + i];
                    a += wls[ea][v*15 + p] * mm;
                }
                msg[ea][v*9 + k] = a * cINVNP[l3];
            }
        }
        __syncthreads();

        // ---- P6: xs1 += lmix(msg, Wlin2) * S_L2 ----
        if (act) {
            float am[9];
            #pragma unroll
            for (int m = 0; m < 9; m++) am[m] = 0;
            #pragma unroll 2
            for (int u = 0; u < 50; u++) {
                float wl[3];
                #pragma unroll
                for (int l = 0; l < 3; l++) wl[l] = Wlin2L[l*2500 + u*50 + v];
                const float* mp = &msg[ea][u*9];
                #pragma unroll
                for (int m = 0; m < 9; m++) {
                    int l = (m == 0) ? 0 : ((m < 4) ? 1 : 2);
                    am[m] += mp[m] * wl[l];
                }
            }
            #pragma unroll
            for (int m = 0; m < 9; m++) xs1[ea][v*9 + m] += am[m] * S_L2;
        }
        __syncthreads();

        // ---- P7: gate matmuls -> tgg (t100 slot is dead now) ----
        if (act) {
            float a0 = 0, a1 = 0;
            #pragma unroll 2
            for (int u = 0; u < 50; u++) {
                float wg = WgL[u*50 + v];
                a0 += xs0[ea][u*9] * wg;
                a1 += xs1[ea][u*9] * wg;
            }
            tgg[ea][v]      = sigf(a0 * S_H);
            tgg[ea][50 + v] = sigf(a1 * S_H);
        }
        __syncthreads();

        // ---- P8: apply gates in LDS (next layer's input) ----
        for (int idx = t; idx < 2*NE*450; idx += 256) {
            int n = idx / 450, i = idx % 450;
            int e = n >> 1, half = n & 1;
            int u = i / 9, m = i % 9;
            float* xp = half ? &xs1[e][0] : &xs0[e][0];
            float val = xp[i];
            float g = tgg[e][half*50 + u];
            xp[i] = (m == 0) ? val * sigf(val) : val * g;
        }
        __syncthreads();
    }

    // ---- Output projection: out[n][m] = S_H * sum_u x[n][u][1+m] * Wout[u] ----
    if (t < NE*6) {
        int e = t / 6, r = t % 6, half = r / 3, m = r % 3;
        const float* xp = half ? &xs1[e][0] : &xs0[e][0];
        float a = 0;
        #pragma unroll 2
        for (int u = 0; u < 50; ++u) a += xp[u*9 + 1 + m] * Wout[u];
        out[((size_t)(2*(e0 + e) + half))*3 + m] = a * S_H;
    }
}

// ---------------- launch ----------------
extern "C" void kernel_launch(void* const* d_in, const int* in_sizes, int n_in,
                              void* d_out, int out_size, void* d_ws, size_t ws_size,
                              hipStream_t stream) {
    const float* node_pos = (const float*)d_in[0];
    const float* bar      = (const float*)d_in[1];
    const float* Wemb     = (const float*)d_in[2];
    const float* Wsc      = (const float*)d_in[3];
    const float* Wlin1    = (const float*)d_in[4];
    const float* W1       = (const float*)d_in[5];
    const float* b1       = (const float*)d_in[6];
    const float* W2       = (const float*)d_in[7];
    const float* Wlin2    = (const float*)d_in[8];
    const float* Wgate    = (const float*)d_in[9];
    const float* Wout     = (const float*)d_in[10];
    float* out = (float*)d_out;

    W3J w3j;
    build_w3j(w3j);

    k_fused<<<E_EDGES/NE, 256, 0, stream>>>(node_pos, bar, Wemb, Wsc, Wlin1,
        W1, b1, W2, Wlin2, Wgate, Wout, out, w3j);
}